// Round 10
// baseline (84.733 us; speedup 1.0000x reference)
//
#include <hip/hip_runtime.h>
#include <hip/hip_bf16.h>
#include <hip/hip_fp16.h>

#define B_ 4
#define N_ 1024
#define C_ 512
#define H_ 8
#define CH_ 64
// tokens = B_*N_ = 4096

typedef _Float16 f16x8 __attribute__((ext_vector_type(8)));
typedef _Float16 f16x4 __attribute__((ext_vector_type(4)));
typedef __fp16 fp16x2 __attribute__((ext_vector_type(2)));
typedef float f32x4 __attribute__((ext_vector_type(4)));

// ---------------- Kernel 1: W [k][n] f32 -> WT [n][k] f16 (5 weights) ----------------
__global__ void transpose_w(const float* __restrict__ Wq, const float* __restrict__ Wk,
                            const float* __restrict__ Wv, const float* __restrict__ Wg,
                            const float* __restrict__ Wo, _Float16* __restrict__ WT) {
  int s = blockIdx.z;
  const float* W = (s == 0) ? Wq : (s == 1) ? Wk : (s == 2) ? Wv : (s == 3) ? Wg : Wo;
  __shared__ float tile[32][33];
  int tx = threadIdx.x & 31, ty = threadIdx.x >> 5;  // 32 x 8
  int k0 = blockIdx.x * 32, n0 = blockIdx.y * 32;
  #pragma unroll
  for (int r = 0; r < 32; r += 8)
    tile[ty + r][tx] = W[(size_t)(k0 + ty + r) * C_ + n0 + tx];
  __syncthreads();
  _Float16* dst = WT + (size_t)s * C_ * C_;
  #pragma unroll
  for (int r = 0; r < 32; r += 8)
    dst[(size_t)(n0 + ty + r) * C_ + k0 + tx] = (_Float16)tile[tx][ty + r];
}

// ---------------- Kernel 2: fused projection GEMM (reads f32 x directly) ----------------
// virtual C [4096 x 2048]: cols 0-511 Q(q_x), 512-1023 K(kv_x), 1024-1535 V(kv_x), 1536-2047 G(q_x)
// A-staging converts f32->f16 in-register (cvt kernel fused away).
// K written head-major [h][b][n][ch]; V written transposed [b][h][ch][N].
__global__ __launch_bounds__(256, 2) void proj_gemm(
    const float* __restrict__ xq, const float* __restrict__ xkv,
    const _Float16* __restrict__ WT, const float* __restrict__ bg,
    _Float16* __restrict__ Qb, _Float16* __restrict__ Kh,
    _Float16* __restrict__ Vt, _Float16* __restrict__ Gb) {
  int nt0 = blockIdx.x * 128;
  int m0 = blockIdx.y * 128;
  int sel = nt0 >> 9;        // 0:Q 1:K 2:V 3:G
  int n0 = nt0 & 511;
  const float* X = (sel == 0 || sel == 3) ? xq : xkv;
  const _Float16* Wt = WT + (size_t)sel * C_ * C_;

  __shared__ __align__(16) char lds[32768];
  char* ldsA = lds;
  char* ldsB = lds + 16384;

  int tid = threadIdx.x;
  int lane = tid & 63, w = tid >> 6;
  int wr = w >> 1, wc = w & 1;
  int lr = lane & 15, lg = lane >> 4;

  f32x4 acc[4][4];
  #pragma unroll
  for (int i = 0; i < 4; i++)
    #pragma unroll
    for (int j = 0; j < 4; j++)
      #pragma unroll
      for (int r = 0; r < 4; r++) acc[i][j][r] = 0.f;

  int srow = tid >> 3, scol = tid & 7;

  for (int k0 = 0; k0 < C_; k0 += 64) {
    __syncthreads();
    #pragma unroll
    for (int p = 0; p < 4; p++) {
      int r = p * 32 + srow;
      const float* xp = X + (size_t)(m0 + r) * C_ + k0 + scol * 8;
      float4 a0 = *(const float4*)xp;
      float4 a1 = *(const float4*)(xp + 4);
      f16x8 hx;
      hx[0] = (_Float16)a0.x; hx[1] = (_Float16)a0.y;
      hx[2] = (_Float16)a0.z; hx[3] = (_Float16)a0.w;
      hx[4] = (_Float16)a1.x; hx[5] = (_Float16)a1.y;
      hx[6] = (_Float16)a1.z; hx[7] = (_Float16)a1.w;
      *(f16x8*)(ldsA + ((r * 128 + scol * 16) ^ ((r & 7) << 4))) = hx;
      *(f16x8*)(ldsB + ((r * 128 + scol * 16) ^ ((r & 7) << 4))) =
          *(const f16x8*)(Wt + (size_t)(n0 + r) * C_ + k0 + scol * 8);
    }
    __syncthreads();
    #pragma unroll
    for (int kh = 0; kh < 2; kh++) {
      f16x8 a[4], b[4];
      #pragma unroll
      for (int i = 0; i < 4; i++) {
        int row = wr * 64 + i * 16 + lr;
        a[i] = *(const f16x8*)(ldsA + ((row * 128 + kh * 64 + lg * 16) ^ ((row & 7) << 4)));
        int col = wc * 64 + i * 16 + lr;
        b[i] = *(const f16x8*)(ldsB + ((col * 128 + kh * 64 + lg * 16) ^ ((col & 7) << 4)));
      }
      #pragma unroll
      for (int i = 0; i < 4; i++)
        #pragma unroll
        for (int j = 0; j < 4; j++)
          acc[i][j] = __builtin_amdgcn_mfma_f32_16x16x32_f16(a[i], b[j], acc[i][j], 0, 0, 0);
    }
  }

  const float inv_sqrt = 0.125f;  // 1/sqrt(64)
  #pragma unroll
  for (int i = 0; i < 4; i++) {
    int token = m0 + wr * 64 + i * 16 + lg * 4;
    #pragma unroll
    for (int j = 0; j < 4; j++) {
      int col = n0 + wc * 64 + j * 16 + lr;
      f32x4 v = acc[i][j];
      if (sel == 0) {
        #pragma unroll
        for (int r = 0; r < 4; r++)
          Qb[(size_t)(token + r) * C_ + col] = (_Float16)(v[r] * inv_sqrt);
      } else if (sel == 1) {
        int bb = token >> 10, nn = token & 1023;
        int hh = col >> 6, ch = col & 63;
        #pragma unroll
        for (int r = 0; r < 4; r++)
          Kh[((size_t)(hh * B_ + bb) * N_ + nn + r) * CH_ + ch] = (_Float16)v[r];
      } else if (sel == 2) {
        int bb = token >> 10, nn = token & 1023;
        int hh = col >> 6, ch = col & 63;
        f16x4 pk;
        #pragma unroll
        for (int r = 0; r < 4; r++) pk[r] = (_Float16)v[r];
        // V^T [b][h][ch][N]: 4 consecutive n -> contiguous f16x4
        *(f16x4*)(Vt + ((size_t)((bb * H_ + hh) * CH_) + ch) * N_ + nn) = pk;
      } else {
        #pragma unroll
        for (int r = 0; r < 4; r++) {
          float x = v[r] + bg[col];
          Gb[(size_t)(token + r) * C_ + col] = (_Float16)(1.f / (1.f + __expf(-x)));
        }
      }
    }
  }
}

// ---------------- Kernel 3: flash attention ----------------
// grid 512: h = bid&7 (XCD affinity), b = (bid>>3)&3, qt = bid>>5 (64-q tiles).
// Block = 256 thr, 4 waves; wave w owns q rows q0+16w..+15. 8 kt of 128 kv rows.
// launch_bounds(256,2): VGPR cap 256 so bp_c/kr/vr prefetches STAY resident.
// Treed max/sum (depth 5, not 31-op serial); acc rescale right after m_new;
// exp->cvt_pkrtz->PV interleaved per ct so MFMA starts ASAP.
__global__ __launch_bounds__(256, 2) void attn(
    const _Float16* __restrict__ Qb, const _Float16* __restrict__ Kh,
    const _Float16* __restrict__ Vt, const _Float16* __restrict__ Gb,
    const float* __restrict__ bias_mask, const float* __restrict__ bias_pair,
    _Float16* __restrict__ Ob) {
  int bid = blockIdx.x;
  int h = bid & 7, b = (bid >> 3) & 3, qt = bid >> 5;
  int q0 = qt * 64;
  int tid = threadIdx.x, lane = tid & 63, w = tid >> 6;
  int lr = lane & 15, lg = lane >> 4;

  __shared__ __align__(16) char lds[32768];
  char* ldsK = lds;            // [128 k][64 ch] f16, 16KB
  char* ldsV = lds + 16384;    // [64 ch][128 k] f16 (V^T), 16KB

  f16x8 qf[2];
  {
    const _Float16* qp = Qb + (size_t)(b * N_ + q0 + w * 16 + lr) * C_ + h * CH_;
    qf[0] = *(const f16x8*)(qp + lg * 8);
    qf[1] = *(const f16x8*)(qp + 32 + lg * 8);
  }

  f32x4 acc_o[4];  // O^T: rows ch = cc*16+lg*4+r, col q = lr
  #pragma unroll
  for (int j = 0; j < 4; j++)
    #pragma unroll
    for (int r = 0; r < 4; r++) acc_o[j][r] = 0.f;
  float m_run = -1e30f, l_run = 0.f;  // per-lane scalars (q = lr)

  int srow = tid >> 3, scol = tid & 7;    // K staging
  int vrow = tid >> 4, vcol = tid & 15;   // V^T staging

  const _Float16* Kbase = Kh + (size_t)((h * B_ + b) * N_) * CH_;
  const _Float16* Vbase = Vt + (size_t)((b * H_ + h) * CH_) * N_;
  const float* bpbase = bias_pair + ((size_t)h * N_ + q0 + w * 16 + lr) * N_ + lg * 4;
  const float* bmbase = bias_mask + b * N_ + lg * 4;

  // prologue prefetches (resident: VGPR cap 256)
  f16x8 kr[4], vr[4];
  #pragma unroll
  for (int pp = 0; pp < 4; pp++) {
    kr[pp] = *(const f16x8*)(Kbase + (size_t)(pp * 32 + srow) * CH_ + scol * 8);
    vr[pp] = *(const f16x8*)(Vbase + (size_t)(pp * 16 + vrow) * N_ + vcol * 8);
  }
  f32x4 bp_c[8];
  #pragma unroll
  for (int ct = 0; ct < 8; ct++) bp_c[ct] = *(const f32x4*)(bpbase + ct * 16);

  for (int kt = 0; kt < 8; kt++) {
    __syncthreads();
    #pragma unroll
    for (int pp = 0; pp < 4; pp++) {
      int r = pp * 32 + srow;
      *(f16x8*)(ldsK + ((r * 128 + scol * 16) ^ ((r & 7) << 4))) = kr[pp];
      int rv = pp * 16 + vrow;
      *(f16x8*)(ldsV + ((rv * 256 + vcol * 16) ^ ((rv & 7) << 4))) = vr[pp];
    }
    __syncthreads();
    if (kt < 7) {
      #pragma unroll
      for (int pp = 0; pp < 4; pp++) {
        kr[pp] = *(const f16x8*)(Kbase + (size_t)((kt + 1) * 128 + pp * 32 + srow) * CH_ + scol * 8);
        vr[pp] = *(const f16x8*)(Vbase + (size_t)(pp * 16 + vrow) * N_ + (kt + 1) * 128 + vcol * 8);
      }
    }
    // S^T init = prefetched bias_pair + bias_mask (L1-hot)
    f32x4 s[8];
    #pragma unroll
    for (int ct = 0; ct < 8; ct++)
      s[ct] = bp_c[ct] + *(const f32x4*)(bmbase + kt * 128 + ct * 16);
    if (kt < 7) {
      #pragma unroll
      for (int ct = 0; ct < 8; ct++)
        bp_c[ct] = *(const f32x4*)(bpbase + (kt + 1) * 128 + ct * 16);
    }
    // S^T += K Q^T
    #pragma unroll
    for (int ct = 0; ct < 8; ct++) {
      #pragma unroll
      for (int kh = 0; kh < 2; kh++) {
        int row = ct * 16 + lr;
        f16x8 kf = *(const f16x8*)(ldsK + ((row * 128 + kh * 64 + lg * 16) ^ ((row & 7) << 4)));
        s[ct] = __builtin_amdgcn_mfma_f32_16x16x32_f16(kf, qf[kh], s[ct], 0, 0, 0);
      }
    }
    // treed max (depth 5)
    float t[8];
    #pragma unroll
    for (int ct = 0; ct < 8; ct++)
      t[ct] = fmaxf(fmaxf(s[ct][0], s[ct][1]), fmaxf(s[ct][2], s[ct][3]));
    float mx = fmaxf(fmaxf(fmaxf(t[0], t[1]), fmaxf(t[2], t[3])),
                     fmaxf(fmaxf(t[4], t[5]), fmaxf(t[6], t[7])));
    mx = fmaxf(mx, __shfl_xor(mx, 16, 64));
    mx = fmaxf(mx, __shfl_xor(mx, 32, 64));
    float m_new = fmaxf(m_run, mx);
    float sc = __expf(m_run - m_new);
    m_run = m_new;
    // rescale acc_o immediately (independent of the exps)
    #pragma unroll
    for (int j = 0; j < 4; j++)
      #pragma unroll
      for (int r = 0; r < 4; r++) acc_o[j][r] *= sc;
    // exp -> pkrtz cvt -> PV per ct (treed sum alongside)
    float psum[8];
    #pragma unroll
    for (int ct = 0; ct < 8; ct++) {
      float p0 = __expf(s[ct][0] - m_new);
      float p1 = __expf(s[ct][1] - m_new);
      float p2 = __expf(s[ct][2] - m_new);
      float p3 = __expf(s[ct][3] - m_new);
      psum[ct] = (p0 + p1) + (p2 + p3);
      fp16x2 lo = __builtin_amdgcn_cvt_pkrtz(p0, p1);
      fp16x2 hi = __builtin_amdgcn_cvt_pkrtz(p2, p3);
      f16x4 pf;
      pf[0] = (_Float16)lo[0]; pf[1] = (_Float16)lo[1];
      pf[2] = (_Float16)hi[0]; pf[3] = (_Float16)hi[1];
      #pragma unroll
      for (int cc = 0; cc < 4; cc++) {
        int vrr = cc * 16 + lr;
        f16x4 vf = *(const f16x4*)(ldsV + ((vrr * 256 + ct * 32 + lg * 8) ^ ((vrr & 7) << 4)));
        acc_o[cc] = __builtin_amdgcn_mfma_f32_16x16x16f16(vf, pf, acc_o[cc], 0, 0, 0);
      }
    }
    float sum = ((psum[0] + psum[1]) + (psum[2] + psum[3])) +
                ((psum[4] + psum[5]) + (psum[6] + psum[7]));
    sum += __shfl_xor(sum, 16, 64);
    sum += __shfl_xor(sum, 32, 64);
    l_run = l_run * sc + sum;
  }

  // epilogue: 1/l, gate, vectorized f16x4 store
  {
    int token = b * N_ + q0 + w * 16 + lr;
    float inv_l = 1.f / l_run;
    #pragma unroll
    for (int cc = 0; cc < 4; cc++) {
      int col = h * CH_ + cc * 16 + lg * 4;
      f16x4 g4 = *(const f16x4*)(Gb + (size_t)token * C_ + col);
      f16x4 o4;
      #pragma unroll
      for (int r = 0; r < 4; r++)
        o4[r] = (_Float16)(acc_o[cc][r] * inv_l * (float)g4[r]);
      *(f16x4*)(Ob + (size_t)token * C_ + col) = o4;
    }
  }
}

// ---------------- Kernel 4: output GEMM + bo ----------------
__global__ __launch_bounds__(256, 2) void out_gemm(
    const _Float16* __restrict__ Ob, const _Float16* __restrict__ WTo,
    const float* __restrict__ bo, float* __restrict__ out) {
  int n0 = blockIdx.x * 128;
  int m0 = blockIdx.y * 128;
  __shared__ __align__(16) char lds[32768];
  char* ldsA = lds;
  char* ldsB = lds + 16384;
  int tid = threadIdx.x;
  int lane = tid & 63, w = tid >> 6;
  int wr = w >> 1, wc = w & 1;
  int lr = lane & 15, lg = lane >> 4;
  f32x4 acc[4][4];
  #pragma unroll
  for (int i = 0; i < 4; i++)
    #pragma unroll
    for (int j = 0; j < 4; j++)
      #pragma unroll
      for (int r = 0; r < 4; r++) acc[i][j][r] = 0.f;
  int srow = tid >> 3, scol = tid & 7;
  for (int k0 = 0; k0 < C_; k0 += 64) {
    __syncthreads();
    #pragma unroll
    for (int p = 0; p < 4; p++) {
      int r = p * 32 + srow;
      *(f16x8*)(ldsA + ((r * 128 + scol * 16) ^ ((r & 7) << 4))) =
          *(const f16x8*)(Ob + (size_t)(m0 + r) * C_ + k0 + scol * 8);
      *(f16x8*)(ldsB + ((r * 128 + scol * 16) ^ ((r & 7) << 4))) =
          *(const f16x8*)(WTo + (size_t)(n0 + r) * C_ + k0 + scol * 8);
    }
    __syncthreads();
    #pragma unroll
    for (int kh = 0; kh < 2; kh++) {
      f16x8 a[4], bfr[4];
      #pragma unroll
      for (int i = 0; i < 4; i++) {
        int row = wr * 64 + i * 16 + lr;
        a[i] = *(const f16x8*)(ldsA + ((row * 128 + kh * 64 + lg * 16) ^ ((row & 7) << 4)));
        int col = wc * 64 + i * 16 + lr;
        bfr[i] = *(const f16x8*)(ldsB + ((col * 128 + kh * 64 + lg * 16) ^ ((col & 7) << 4)));
      }
      #pragma unroll
      for (int i = 0; i < 4; i++)
        #pragma unroll
        for (int j = 0; j < 4; j++)
          acc[i][j] = __builtin_amdgcn_mfma_f32_16x16x32_f16(a[i], bfr[j], acc[i][j], 0, 0, 0);
    }
  }
  #pragma unroll
  for (int i = 0; i < 4; i++) {
    int token = m0 + wr * 64 + i * 16 + lg * 4;
    #pragma unroll
    for (int j = 0; j < 4; j++) {
      int col = n0 + wc * 64 + j * 16 + lr;
      float bb = bo[col];
      #pragma unroll
      for (int r = 0; r < 4; r++)
        out[(size_t)(token + r) * C_ + col] = acc[i][j][r] + bb;
    }
  }
}

extern "C" void kernel_launch(void* const* d_in, const int* in_sizes, int n_in,
                              void* d_out, int out_size, void* d_ws, size_t ws_size,
                              hipStream_t stream) {
  const float* q_x = (const float*)d_in[0];
  const float* kv_x = (const float*)d_in[1];
  const float* bias_mask = (const float*)d_in[2];
  const float* bias_pair = (const float*)d_in[3];
  const float* Wq = (const float*)d_in[4];
  const float* Wk = (const float*)d_in[5];
  const float* Wv = (const float*)d_in[6];
  const float* Wg = (const float*)d_in[7];
  const float* bg = (const float*)d_in[8];
  const float* Wo = (const float*)d_in[9];
  const float* bo = (const float*)d_in[10];
  float* out = (float*)d_out;

  char* ws = (char*)d_ws;
  const size_t MB = 1024 * 1024;
  _Float16* WT = (_Float16*)(ws + 0);          // 2.5 MB (5 x 512 x 512 f16)
  _Float16* Qb = (_Float16*)(ws + 3 * MB);     // 4 MB
  _Float16* Kh = (_Float16*)(ws + 7 * MB);     // 4 MB  [h][b][n][ch]
  _Float16* Vt = (_Float16*)(ws + 11 * MB);    // 4 MB  [b][h][ch][N]
  _Float16* Gb = (_Float16*)(ws + 15 * MB);    // 4 MB (f16 gate)
  _Float16* Ob = (_Float16*)(ws + 19 * MB);    // 4 MB

  transpose_w<<<dim3(16, 16, 5), 256, 0, stream>>>(Wq, Wk, Wv, Wg, Wo, WT);
  proj_gemm<<<dim3(16, 32), 256, 0, stream>>>(q_x, kv_x, WT, bg, Qb, Kh, Vt, Gb);
  attn<<<512, 256, 0, stream>>>(Qb, Kh, Vt, Gb, bias_mask, bias_pair, Ob);
  out_gemm<<<dim3(4, 32), 256, 0, stream>>>(Ob, WT + 4 * (size_t)C_ * C_, bo, out);
}